// Round 3
// baseline (96.990 us; speedup 1.0000x reference)
//
#include <hip/hip_runtime.h>
#include <math.h>

#define EPSF 1e-6f

constexpr int B_ = 8, Q_ = 900, C1_ = 92, T_ = 1600;
constexpr int NROW = B_ * Q_;    // 7200
constexpr int RPB = 16;          // rows per block
constexpr int TPB = 320;         // threads (5 waves); gridDim.x * TPB == T_
constexpr int LG = RPB * C1_;    // 1472 staged logits per block

// Fully fused: per block, stage 16 rows of logits -> in-LDS softmax ->
// pairwise cost vs this block's 320 targets. One dispatch, no workspace.
__global__ __launch_bounds__(TPB) void fused_cost_kernel(
    const float* __restrict__ logits,   // [NROW, 92]
    const float* __restrict__ pbox,     // [NROW, 4]
    const int*   __restrict__ ids,      // [T]
    const float* __restrict__ tbox,     // [T, 4]
    float* __restrict__ out)            // [NROW, T]
{
    __shared__ float slog[LG];          // logits -> probs (in place), dense 92
    __shared__ float spred[RPB * 8];    // per-row derived box data
    __shared__ float sred[RPB * 20];    // reduction scratch
    __shared__ float smax[RPB];
    __shared__ float sinv[RPB];

    const int tid  = threadIdx.x;
    const int t    = blockIdx.x * TPB + tid;
    const int row0 = blockIdx.y * RPB;

    // ---- stage 16 rows of logits: 1472 contiguous floats = 368 float4 ----
    {
        const float4* g4 = (const float4*)(logits + (size_t)row0 * C1_);
        float4* s4 = (float4*)slog;
        s4[tid] = g4[tid];
        if (tid < LG / 4 - TPB)                 // 368 - 320 = 48
            s4[tid + TPB] = g4[tid + TPB];
    }

    // ---- per-target derived data (registers, coalesced loads) ----
    const float4 tb4 = *(const float4*)(tbox + (size_t)t * 4);
    const int id = ids[t];
    const float tx1 = tb4.x, ty1 = tb4.y, tx2 = tb4.z, ty2 = tb4.w;
    const float w2 = tx2 - tx1, h2 = ty2 - ty1;
    const float area2  = w2 * h2;
    const float atan2t = atanf(w2 / (h2 + EPSF));
    const float sx2 = tx1 + tx2, sy2 = ty1 + ty2;

    // ---- per-row derived box data (16 threads) ----
    if (tid < RPB) {
        const float4 p = *(const float4*)(pbox + (size_t)(row0 + tid) * 4);
        const float w = p.z - p.x, h = p.w - p.y;
        float* d = spred + tid * 8;
        d[0] = p.x; d[1] = p.y; d[2] = p.z; d[3] = p.w;
        d[4] = w * h;
        d[5] = atanf(w / (h + EPSF));
        d[6] = p.x + p.z;
        d[7] = p.y + p.w;
    }

    __syncthreads();

    // ---- in-LDS softmax over the 16 staged rows: 20 threads per row ----
    const int r = tid / 20;                  // 0..15
    const int j = tid - r * 20;              // 0..19
    {
        float m = -INFINITY;
        for (int e = j; e < C1_; e += 20) m = fmaxf(m, slog[r * C1_ + e]);
        sred[r * 20 + j] = m;
    }
    __syncthreads();
    if (j == 0) {
        float mm = sred[r * 20];
        #pragma unroll
        for (int k = 1; k < 20; ++k) mm = fmaxf(mm, sred[r * 20 + k]);
        smax[r] = mm;
    }
    __syncthreads();
    {
        const float mm = smax[r];
        float s = 0.0f;
        for (int e = j; e < C1_; e += 20) s += __expf(slog[r * C1_ + e] - mm);
        sred[r * 20 + j] = s;
    }
    __syncthreads();
    if (j == 0) {
        float ss = 0.0f;
        #pragma unroll
        for (int k = 0; k < 20; ++k) ss += sred[r * 20 + k];
        sinv[r] = 1.0f / ss;
    }
    __syncthreads();
    // normalize in place: slog[i] = softmax prob
    for (int i = tid; i < LG; i += TPB) {
        const int rr = i / C1_;              // magic-mul, compile-time const
        slog[i] = __expf(slog[i] - smax[rr]) * sinv[rr];
    }
    __syncthreads();

    // ---- pairwise cost: 16 rows x my target ----
    float* outp = out + (size_t)row0 * T_ + t;
    #pragma unroll 4
    for (int rr = 0; rr < RPB; ++rr) {
        const float4 pa = *(const float4*)(spred + rr * 8);
        const float4 pb = *(const float4*)(spred + rr * 8 + 4);
        const float px1 = pa.x, py1 = pa.y, px2 = pa.z, py2 = pa.w;
        const float area1 = pb.x, atan1t = pb.y, sx1 = pb.z, sy1 = pb.w;

        const float prob = slog[rr * C1_ + id];

        const float ix1 = fmaxf(px1, tx1);
        const float iy1 = fmaxf(py1, ty1);
        const float ix2 = fminf(px2, tx2);
        const float iy2 = fminf(py2, ty2);
        const float inter = fmaxf(ix2 - ix1, 0.0f) * fmaxf(iy2 - iy1, 0.0f);
        const float uni = area1 + area2 - inter;
        const float iou = inter * __builtin_amdgcn_rcpf(uni + EPSF);

        const float cw = fmaxf(px2, tx2) - fminf(px1, tx1);
        const float ch = fmaxf(py2, ty2) - fminf(py1, ty1);
        const float diag = cw * cw + ch * ch;
        const float dx = sx2 - sx1, dy = sy2 - sy1;
        const float cdist = dx * dx + dy * dy;
        const float dist_pen = cdist * __builtin_amdgcn_rcpf(diag + EPSF) * 0.25f;

        const float dat = atan2t - atan1t;
        const float v = (4.0f / (float)(M_PI * M_PI)) * dat * dat;
        const float av = v * v * __builtin_amdgcn_rcpf(1.0f + EPSF - iou + v);

        const float ciou = iou - dist_pen - av;

        const float cost_bbox = fabsf(px1 - tx1) + fabsf(py1 - ty1) +
                                fabsf(px2 - tx2) + fabsf(py2 - ty2);

        __builtin_nontemporal_store(cost_bbox - prob - ciou, outp);
        outp += T_;
    }
}

extern "C" void kernel_launch(void* const* d_in, const int* in_sizes, int n_in,
                              void* d_out, int out_size, void* d_ws, size_t ws_size,
                              hipStream_t stream) {
    const float* logits = (const float*)d_in[0];  // [8,900,92]
    const float* pbox   = (const float*)d_in[1];  // [8,900,4]
    const int*   ids    = (const int*)d_in[2];    // [1600]
    const float* tbox   = (const float*)d_in[3];  // [1600,4]
    float* out = (float*)d_out;

    fused_cost_kernel<<<dim3(T_ / TPB, NROW / RPB), TPB, 0, stream>>>(
        logits, pbox, ids, tbox, out);
}